// Round 9
// baseline (377.100 us; speedup 1.0000x reference)
//
#include <hip/hip_runtime.h>

#define D_MODEL 768
#define NHEAD   12
#define HDIM    64
#define SEQ     1024
#define BATCH   4
#define QBLK    16
#define KVBLK   64
#define NT      (SEQ / KVBLK)

typedef __attribute__((ext_vector_type(8))) short short8v;
typedef __attribute__((ext_vector_type(4))) float f32x4;

__device__ __forceinline__ ushort f2bf(float f) {
    union { float f; unsigned u; } c; c.f = f;
    unsigned r = c.u + 0x7fffu + ((c.u >> 16) & 1u);   // RNE for normal values
    return (ushort)(r >> 16);
}

// ---------------------------------------------------------------------------
// Cast fp32 -> bf16 (elementwise, 4/thread)
// ---------------------------------------------------------------------------
__global__ void cast_bf16_kernel(const float* __restrict__ src,
                                 ushort* __restrict__ dst, int n4)
{
    int idx = blockIdx.x * blockDim.x + threadIdx.x;
    if (idx >= n4) return;
    float4 v = ((const float4*)src)[idx];
    ushort4 o;
    o.x = f2bf(v.x); o.y = f2bf(v.y); o.z = f2bf(v.z); o.w = f2bf(v.w);
    ((ushort4*)dst)[idx] = o;
}

// ---------------------------------------------------------------------------
// Cast + transpose four 768x768 fp32 weights to bf16 [N][K] in ONE launch.
// ---------------------------------------------------------------------------
__global__ __launch_bounds__(256) void castT4_kernel(
    const float* __restrict__ W0, const float* __restrict__ W1,
    const float* __restrict__ W2, const float* __restrict__ W3,
    ushort* __restrict__ D0, ushort* __restrict__ D1,
    ushort* __restrict__ D2, ushort* __restrict__ D3)
{
    __shared__ float tile[32][33];
    const int z = blockIdx.z;
    const float* W = (z == 0) ? W0 : (z == 1) ? W1 : (z == 2) ? W2 : W3;
    ushort*     D = (z == 0) ? D0 : (z == 1) ? D1 : (z == 2) ? D2 : D3;

    const int kb  = blockIdx.x * 32;
    const int nb  = blockIdx.y * 32;
    const int tid = threadIdx.x;
    const int r   = tid >> 3;
    const int c4  = (tid & 7) * 4;

    float4 v = *(const float4*)(W + (size_t)(kb + r) * 768 + nb + c4);
    tile[r][c4 + 0] = v.x; tile[r][c4 + 1] = v.y;
    tile[r][c4 + 2] = v.z; tile[r][c4 + 3] = v.w;
    __syncthreads();

    ushort4 o;
    o.x = f2bf(tile[c4 + 0][r]);
    o.y = f2bf(tile[c4 + 1][r]);
    o.z = f2bf(tile[c4 + 2][r]);
    o.w = f2bf(tile[c4 + 3][r]);
    *(ushort4*)(D + (size_t)(nb + r) * 768 + kb + c4) = o;
}

// ---------------------------------------------------------------------------
// bf16 MFMA GEMM (m97 structure). BF16OUT: 0=f32 out, 1=bf16 out.
// If VT != nullptr, the sel==2 slice (V) is written TRANSPOSED into
// vt[b][h][d][j] directly from the accumulators (4 consecutive rows of a
// fragment = 4 consecutive j -> one ushort4 store). Kills the vT pass.
// ---------------------------------------------------------------------------
template<int BF16OUT>
__global__ __launch_bounds__(256) void gemm_bf16_kernel(
    const ushort* __restrict__ A, const ushort* __restrict__ BT,
    void* __restrict__ C0v, void* __restrict__ C1v, void* __restrict__ C2v,
    const float* __restrict__ bias, ushort* __restrict__ VT)
{
    __shared__ __align__(16) ushort As[128 * 32];
    __shared__ __align__(16) ushort Bs[128 * 32];

    const int bm  = blockIdx.x * 128;
    const int bnG = blockIdx.y * 128;
    const int sel = bnG / 768;
    void* Cv = (sel == 0) ? C0v : ((sel == 1) ? C1v : C2v);
    const int ncol0 = bnG - sel * 768;

    const int tid  = threadIdx.x;
    const int lane = tid & 63;
    const int wave = tid >> 6;
    const int wm = wave >> 1, wn = wave & 1;

    f32x4 acc[4][4];
    #pragma unroll
    for (int i = 0; i < 4; i++)
        #pragma unroll
        for (int j = 0; j < 4; j++)
            acc[i][j] = (f32x4){0.f, 0.f, 0.f, 0.f};

    const int sr = tid >> 2;
    const int sk = (tid & 3) * 8;
    const ushort* Ap = A  + (size_t)(bm  + sr) * 768 + sk;
    const ushort* Bp = BT + (size_t)(bnG + sr) * 768 + sk;
    char* AsDst = (char*)As + tid * 16;
    char* BsDst = (char*)Bs + tid * 16;

    for (int k0 = 0; k0 < 768; k0 += 32) {
        __syncthreads();
        __builtin_amdgcn_global_load_lds(
            (const __attribute__((address_space(1))) void*)(Ap + k0),
            (__attribute__((address_space(3))) void*)AsDst, 16, 0, 0);
        __builtin_amdgcn_global_load_lds(
            (const __attribute__((address_space(1))) void*)(Ap + (size_t)64 * 768 + k0),
            (__attribute__((address_space(3))) void*)(AsDst + 4096), 16, 0, 0);
        __builtin_amdgcn_global_load_lds(
            (const __attribute__((address_space(1))) void*)(Bp + k0),
            (__attribute__((address_space(3))) void*)BsDst, 16, 0, 0);
        __builtin_amdgcn_global_load_lds(
            (const __attribute__((address_space(1))) void*)(Bp + (size_t)64 * 768 + k0),
            (__attribute__((address_space(3))) void*)(BsDst + 4096), 16, 0, 0);
        __syncthreads();

        short8v a[4], b[4];
        #pragma unroll
        for (int i = 0; i < 4; i++)
            a[i] = *(const short8v*)((const char*)As +
                     (wm * 64 + i * 16 + (lane & 15)) * 64 + (lane >> 4) * 16);
        #pragma unroll
        for (int j = 0; j < 4; j++)
            b[j] = *(const short8v*)((const char*)Bs +
                     (wn * 64 + j * 16 + (lane & 15)) * 64 + (lane >> 4) * 16);
        #pragma unroll
        for (int i = 0; i < 4; i++)
            #pragma unroll
            for (int j = 0; j < 4; j++)
                acc[i][j] = __builtin_amdgcn_mfma_f32_16x16x32_bf16(a[i], b[j], acc[i][j], 0, 0, 0);
    }

    const int cc = lane & 15, cr = lane >> 4;
    if (BF16OUT && VT != nullptr && sel == 2) {
        // V slice: write transposed vt[b][h][d][j]
        #pragma unroll
        for (int j = 0; j < 4; j++) {
            const int hcol = ncol0 + wn * 64 + j * 16 + cc;   // 0..767
            const int h2 = hcol >> 6, dd = hcol & 63;
            #pragma unroll
            for (int i = 0; i < 4; i++) {
                const int row0 = bm + wm * 64 + i * 16 + cr * 4;  // 4 consecutive
                const int bb = row0 >> 10, jj = row0 & 1023;
                ushort4 o;
                o.x = f2bf(acc[i][j][0]); o.y = f2bf(acc[i][j][1]);
                o.z = f2bf(acc[i][j][2]); o.w = f2bf(acc[i][j][3]);
                *(ushort4*)(VT + (((size_t)bb * NHEAD + h2) * HDIM + dd) * SEQ + jj) = o;
            }
        }
        return;
    }
    #pragma unroll
    for (int j = 0; j < 4; j++) {
        const int col = ncol0 + wn * 64 + j * 16 + cc;
        const float badd = bias ? bias[col] : 0.f;
        #pragma unroll
        for (int i = 0; i < 4; i++) {
            #pragma unroll
            for (int r = 0; r < 4; r++) {
                const int row = bm + wm * 64 + i * 16 + cr * 4 + r;
                if (BF16OUT)
                    ((ushort*)Cv)[(size_t)row * 768 + col] = f2bf(acc[i][j][r] + badd);
                else
                    ((float*)Cv)[(size_t)row * 768 + col] = acc[i][j][r] + badd;
            }
        }
    }
}

// ---------------------------------------------------------------------------
// Talking-heads attention, MFMA — v4: KVBLK=64, double-buffered LDS,
// 1 barrier/tile (phase A, alternating buffers) + 2 barriers/tile (phase B).
// Lane covers cols {lc*8..+7} and {32+lc*8..+7} (matches PV A-frag k-layout).
// exp2f with log2e folded into pre weights (identical across phases).
// ---------------------------------------------------------------------------
__global__ __launch_bounds__(768, 1) void attn_mfma_kernel(
    const ushort* __restrict__ qb, const ushort* __restrict__ kb,
    const ushort* __restrict__ vt, const float* __restrict__ pre_attn,
    const float* __restrict__ post_attn, ushort* __restrict__ avb)
{
    __shared__ __align__(16) float sA[NHEAD][QBLK][68];   // 52.2 KB
    __shared__ __align__(16) float sE[NHEAD][QBLK][68];   // 52.2 KB
    __shared__ float pre_l[NHEAD * NHEAD];
    __shared__ float post_l[NHEAD * NHEAD];
    __shared__ float l_lds[NHEAD][QBLK];

    const int i0  = blockIdx.x * QBLK;
    const int b   = blockIdx.y;
    const int tid = threadIdx.x;
    const int lane = tid & 63;
    const int h    = tid >> 6;          // wave = head (dest head g in phase B)

    // fold 1/sqrt(64) and log2(e) so exp(mix) == exp2(mix')
    if (tid < 144) pre_l[tid] = pre_attn[tid] * (0.125f * 1.44269504f);
    else if (tid < 288) post_l[tid - 144] = post_attn[tid - 144];

    const int lr = lane & 15;
    const int lc = lane >> 4;

    const ushort* qbase = qb + ((size_t)b * SEQ + i0 + lr) * D_MODEL + h * HDIM + lc * 8;
    const short8v a_q0 = *(const short8v*)(qbase);
    const short8v a_q1 = *(const short8v*)(qbase + 32);

    const ushort* kbase  = kb + ((size_t)b * SEQ + lr) * D_MODEL + h * HDIM + lc * 8;
    const ushort* vtbase = vt + (((size_t)b * NHEAD + h) * HDIM + lr) * SEQ + lc * 8;

    // ======================= Phase A: row sums =======================
    float lsum = 0.f;
    for (int t = 0; t < NT; t++) {
        const int j0 = t * KVBLK;
        float (*S)[QBLK][68] = (t & 1) ? sE : sA;

        f32x4 sf[4];
        #pragma unroll
        for (int cf = 0; cf < 4; cf++) {
            const ushort* kp = kbase + (size_t)(j0 + cf * 16) * D_MODEL;
            short8v bk0 = *(const short8v*)(kp);
            short8v bk1 = *(const short8v*)(kp + 32);
            f32x4 a = (f32x4){0.f, 0.f, 0.f, 0.f};
            a = __builtin_amdgcn_mfma_f32_16x16x32_bf16(a_q0, bk0, a, 0, 0, 0);
            a = __builtin_amdgcn_mfma_f32_16x16x32_bf16(a_q1, bk1, a, 0, 0, 0);
            sf[cf] = a;
        }
        #pragma unroll
        for (int cf = 0; cf < 4; cf++)
            #pragma unroll
            for (int rr = 0; rr < 4; rr++)
                S[h][lc * 4 + rr][cf * 16 + lr] = sf[cf][rr];
        __syncthreads();

        float mix[16];
        #pragma unroll
        for (int c = 0; c < 16; c++) mix[c] = 0.f;
        #pragma unroll
        for (int hh = 0; hh < NHEAD; hh++) {
            const float w = pre_l[hh * NHEAD + h];
            const float* row = &S[hh][lr][0];
            const float4 a0 = *(const float4*)(row + lc * 8);
            const float4 a1 = *(const float4*)(row + lc * 8 + 4);
            const float4 a2 = *(const float4*)(row + 32 + lc * 8);
            const float4 a3 = *(const float4*)(row + 36 + lc * 8);
            mix[0]  = fmaf(a0.x, w, mix[0]);  mix[1]  = fmaf(a0.y, w, mix[1]);
            mix[2]  = fmaf(a0.z, w, mix[2]);  mix[3]  = fmaf(a0.w, w, mix[3]);
            mix[4]  = fmaf(a1.x, w, mix[4]);  mix[5]  = fmaf(a1.y, w, mix[5]);
            mix[6]  = fmaf(a1.z, w, mix[6]);  mix[7]  = fmaf(a1.w, w, mix[7]);
            mix[8]  = fmaf(a2.x, w, mix[8]);  mix[9]  = fmaf(a2.y, w, mix[9]);
            mix[10] = fmaf(a2.z, w, mix[10]); mix[11] = fmaf(a2.w, w, mix[11]);
            mix[12] = fmaf(a3.x, w, mix[12]); mix[13] = fmaf(a3.y, w, mix[13]);
            mix[14] = fmaf(a3.z, w, mix[14]); mix[15] = fmaf(a3.w, w, mix[15]);
        }
        #pragma unroll
        for (int c = 0; c < 16; c++) lsum += exp2f(mix[c]);
    }
    float lrow = lsum;
    lrow += __shfl_xor(lrow, 16);
    lrow += __shfl_xor(lrow, 32);
    if (lc == 0) l_lds[h][lr] = lrow;
    __syncthreads();

    float il[NHEAD];
    #pragma unroll
    for (int hh = 0; hh < NHEAD; hh++) il[hh] = 1.f / l_lds[hh][lr];

    // ======================= Phase B: P + PV =======================
    f32x4 o_acc[4];
    #pragma unroll
    for (int d = 0; d < 4; d++) o_acc[d] = (f32x4){0.f, 0.f, 0.f, 0.f};

    for (int t = 0; t < NT; t++) {
        const int j0 = t * KVBLK;

        f32x4 sf[4];
        #pragma unroll
        for (int cf = 0; cf < 4; cf++) {
            const ushort* kp = kbase + (size_t)(j0 + cf * 16) * D_MODEL;
            short8v bk0 = *(const short8v*)(kp);
            short8v bk1 = *(const short8v*)(kp + 32);
            f32x4 a = (f32x4){0.f, 0.f, 0.f, 0.f};
            a = __builtin_amdgcn_mfma_f32_16x16x32_bf16(a_q0, bk0, a, 0, 0, 0);
            a = __builtin_amdgcn_mfma_f32_16x16x32_bf16(a_q1, bk1, a, 0, 0, 0);
            sf[cf] = a;
        }
        // stage raw S -> sA (prior readers of sA finished before bar3_{t-1})
        #pragma unroll
        for (int cf = 0; cf < 4; cf++)
            #pragma unroll
            for (int rr = 0; rr < 4; rr++)
                sA[h][lc * 4 + rr][cf * 16 + lr] = sf[cf][rr];
        __syncthreads();                       // bar2: S visible

        float mix[16];
        #pragma unroll
        for (int c = 0; c < 16; c++) mix[c] = 0.f;
        #pragma unroll
        for (int hh = 0; hh < NHEAD; hh++) {
            const float w = pre_l[hh * NHEAD + h];
            const float* row = &sA[hh][lr][0];
            const float4 a0 = *(const float4*)(row + lc * 8);
            const float4 a1 = *(const float4*)(row + lc * 8 + 4);
            const float4 a2 = *(const float4*)(row + 32 + lc * 8);
            const float4 a3 = *(const float4*)(row + 36 + lc * 8);
            mix[0]  = fmaf(a0.x, w, mix[0]);  mix[1]  = fmaf(a0.y, w, mix[1]);
            mix[2]  = fmaf(a0.z, w, mix[2]);  mix[3]  = fmaf(a0.w, w, mix[3]);
            mix[4]  = fmaf(a1.x, w, mix[4]);  mix[5]  = fmaf(a1.y, w, mix[5]);
            mix[6]  = fmaf(a1.z, w, mix[6]);  mix[7]  = fmaf(a1.w, w, mix[7]);
            mix[8]  = fmaf(a2.x, w, mix[8]);  mix[9]  = fmaf(a2.y, w, mix[9]);
            mix[10] = fmaf(a2.z, w, mix[10]); mix[11] = fmaf(a2.w, w, mix[11]);
            mix[12] = fmaf(a3.x, w, mix[12]); mix[13] = fmaf(a3.y, w, mix[13]);
            mix[14] = fmaf(a3.z, w, mix[14]); mix[15] = fmaf(a3.w, w, mix[15]);
        }
        float e[16];
        #pragma unroll
        for (int c = 0; c < 16; c++) e[c] = exp2f(mix[c]);   // same fp ops as phase A

        // restage e -> sE (prior post-readers finished before bar2 above)
        {
            float* row = &sE[h][lr][0];
            *(float4*)(row + lc * 8)      = *(float4*)(&e[0]);
            *(float4*)(row + lc * 8 + 4)  = *(float4*)(&e[4]);
            *(float4*)(row + 32 + lc * 8) = *(float4*)(&e[8]);
            *(float4*)(row + 36 + lc * 8) = *(float4*)(&e[12]);
        }
        __syncthreads();                       // bar3: e visible

        float pm[16];
        #pragma unroll
        for (int c = 0; c < 16; c++) pm[c] = 0.f;
        #pragma unroll
        for (int hh = 0; hh < NHEAD; hh++) {
            const float w = post_l[hh * NHEAD + h] * il[hh];
            const float* row = &sE[hh][lr][0];
            const float4 a0 = *(const float4*)(row + lc * 8);
            const float4 a1 = *(const float4*)(row + lc * 8 + 4);
            const float4 a2 = *(const float4*)(row + 32 + lc * 8);
            const float4 a3 = *(const float4*)(row + 36 + lc * 8);
            pm[0]  = fmaf(a0.x, w, pm[0]);  pm[1]  = fmaf(a0.y, w, pm[1]);
            pm[2]  = fmaf(a0.z, w, pm[2]);  pm[3]  = fmaf(a0.w, w, pm[3]);
            pm[4]  = fmaf(a1.x, w, pm[4]);  pm[5]  = fmaf(a1.y, w, pm[5]);
            pm[6]  = fmaf(a1.z, w, pm[6]);  pm[7]  = fmaf(a1.w, w, pm[7]);
            pm[8]  = fmaf(a2.x, w, pm[8]);  pm[9]  = fmaf(a2.y, w, pm[9]);
            pm[10] = fmaf(a2.z, w, pm[10]); pm[11] = fmaf(a2.w, w, pm[11]);
            pm[12] = fmaf(a3.x, w, pm[12]); pm[13] = fmaf(a3.y, w, pm[13]);
            pm[14] = fmaf(a3.z, w, pm[14]); pm[15] = fmaf(a3.w, w, pm[15]);
        }
        short8v pa0, pa1;
        #pragma unroll
        for (int c = 0; c < 8; c++) {
            ((ushort*)&pa0)[c] = f2bf(pm[c]);
            ((ushort*)&pa1)[c] = f2bf(pm[8 + c]);
        }

        #pragma unroll
        for (int d = 0; d < 4; d++) {
            short8v bv0 = *(const short8v*)(vtbase + (size_t)(d * 16) * SEQ + j0);
            short8v bv1 = *(const short8v*)(vtbase + (size_t)(d * 16) * SEQ + j0 + 32);
            o_acc[d] = __builtin_amdgcn_mfma_f32_16x16x32_bf16(pa0, bv0, o_acc[d], 0, 0, 0);
            o_acc[d] = __builtin_amdgcn_mfma_f32_16x16x32_bf16(pa1, bv1, o_acc[d], 0, 0, 0);
        }
    }

    // ---- store O (row = lc*4+rr, col = d*16+lr) ----
    #pragma unroll
    for (int d = 0; d < 4; d++)
        #pragma unroll
        for (int rr = 0; rr < 4; rr++)
            avb[(((size_t)b * NHEAD + h) * SEQ + i0 + lc * 4 + rr) * HDIM + d * 16 + lr]
                = f2bf(o_acc[d][rr]);
}

// ---------------------------------------------------------------------------
extern "C" void kernel_launch(void* const* d_in, const int* in_sizes, int n_in,
                              void* d_out, int out_size, void* d_ws, size_t ws_size,
                              hipStream_t stream)
{
    const float* x    = (const float*)d_in[0];
    const float* Wq   = (const float*)d_in[1];
    const float* Wk   = (const float*)d_in[2];
    const float* Wv   = (const float*)d_in[3];
    const float* pre  = (const float*)d_in[4];
    const float* post = (const float*)d_in[5];
    const float* Wo   = (const float*)d_in[6];
    const float* bo   = (const float*)d_in[7];
    float* out = (float*)d_out;

    const size_t SZ = (size_t)BATCH * SEQ * D_MODEL;   // 3,145,728
    ushort* qbf    = (ushort*)d_ws;
    ushort* kbf    = qbf + SZ;
    ushort* vt     = kbf + SZ;              // [b][h][d][j] written by GEMM epilogue
    ushort* xb_avb = vt  + SZ;              // x_bf16 for QKV GEMM, av_bf16 after
    ushort* qkvT   = xb_avb + SZ;           // [2304][768]: WqT|WkT|WvT
    ushort* WoT    = qkvT + (size_t)2304 * 768;
    // total 29.9 MB

    cast_bf16_kernel<<<(int)(SZ / 4 + 255) / 256, 256, 0, stream>>>(x, xb_avb, (int)(SZ / 4));
    castT4_kernel<<<dim3(24, 24, 4), 256, 0, stream>>>(
        Wq, Wk, Wv, Wo,
        qkvT, qkvT + (size_t)768 * 768, qkvT + (size_t)2 * 768 * 768, WoT);

    // fused QKV projection; V slice written transposed into vt
    gemm_bf16_kernel<1><<<dim3(32, 18), 256, 0, stream>>>(
        xb_avb, qkvT, qbf, kbf, nullptr, nullptr, vt);

    attn_mfma_kernel<<<dim3(SEQ / QBLK, BATCH), 768, 0, stream>>>(
        qbf, kbf, vt, pre, post, xb_avb);

    gemm_bf16_kernel<0><<<dim3(32, 6), 256, 0, stream>>>(
        xb_avb, WoT, out, out, out, bo, nullptr);
}

// Round 11
// 343.002 us; speedup vs baseline: 1.0994x; 1.0994x over previous
//
#include <hip/hip_runtime.h>

#define D_MODEL 768
#define NHEAD   12
#define HDIM    64
#define SEQ     1024
#define BATCH   4
#define QBLK    16
#define KVBLK   64
#define NT      (SEQ / KVBLK)
#define SPITCH  834   // dwords per S row: 64*13 + 2 pad (stride*4 % 32 == 8 -> lc spread)

typedef __attribute__((ext_vector_type(8))) short short8v;
typedef __attribute__((ext_vector_type(4))) float f32x4;

__device__ __forceinline__ ushort f2bf(float f) {
    union { float f; unsigned u; } c; c.f = f;
    unsigned r = c.u + 0x7fffu + ((c.u >> 16) & 1u);   // RNE for normal values
    return (ushort)(r >> 16);
}

// ---------------------------------------------------------------------------
// Cast fp32 -> bf16 (elementwise, 4/thread)
// ---------------------------------------------------------------------------
__global__ void cast_bf16_kernel(const float* __restrict__ src,
                                 ushort* __restrict__ dst, int n4)
{
    int idx = blockIdx.x * blockDim.x + threadIdx.x;
    if (idx >= n4) return;
    float4 v = ((const float4*)src)[idx];
    ushort4 o;
    o.x = f2bf(v.x); o.y = f2bf(v.y); o.z = f2bf(v.z); o.w = f2bf(v.w);
    ((ushort4*)dst)[idx] = o;
}

// ---------------------------------------------------------------------------
// Cast + transpose four 768x768 fp32 weights to bf16 [N][K] in ONE launch.
// ---------------------------------------------------------------------------
__global__ __launch_bounds__(256) void castT4_kernel(
    const float* __restrict__ W0, const float* __restrict__ W1,
    const float* __restrict__ W2, const float* __restrict__ W3,
    ushort* __restrict__ D0, ushort* __restrict__ D1,
    ushort* __restrict__ D2, ushort* __restrict__ D3)
{
    __shared__ float tile[32][33];
    const int z = blockIdx.z;
    const float* W = (z == 0) ? W0 : (z == 1) ? W1 : (z == 2) ? W2 : W3;
    ushort*     D = (z == 0) ? D0 : (z == 1) ? D1 : (z == 2) ? D2 : D3;

    const int kb  = blockIdx.x * 32;
    const int nb  = blockIdx.y * 32;
    const int tid = threadIdx.x;
    const int r   = tid >> 3;
    const int c4  = (tid & 7) * 4;

    float4 v = *(const float4*)(W + (size_t)(kb + r) * 768 + nb + c4);
    tile[r][c4 + 0] = v.x; tile[r][c4 + 1] = v.y;
    tile[r][c4 + 2] = v.z; tile[r][c4 + 3] = v.w;
    __syncthreads();

    ushort4 o;
    o.x = f2bf(tile[c4 + 0][r]);
    o.y = f2bf(tile[c4 + 1][r]);
    o.z = f2bf(tile[c4 + 2][r]);
    o.w = f2bf(tile[c4 + 3][r]);
    *(ushort4*)(D + (size_t)(nb + r) * 768 + kb + c4) = o;
}

// ---------------------------------------------------------------------------
// bf16 MFMA GEMM (m97 structure). BF16OUT: 0=f32 out, 1=bf16 out.
// If VT != nullptr, the sel==2 slice (V) is written TRANSPOSED into
// vt[b][h][d][j] directly from the accumulators.
// ---------------------------------------------------------------------------
template<int BF16OUT>
__global__ __launch_bounds__(256) void gemm_bf16_kernel(
    const ushort* __restrict__ A, const ushort* __restrict__ BT,
    void* __restrict__ C0v, void* __restrict__ C1v, void* __restrict__ C2v,
    const float* __restrict__ bias, ushort* __restrict__ VT)
{
    __shared__ __align__(16) ushort As[128 * 32];
    __shared__ __align__(16) ushort Bs[128 * 32];

    const int bm  = blockIdx.x * 128;
    const int bnG = blockIdx.y * 128;
    const int sel = bnG / 768;
    void* Cv = (sel == 0) ? C0v : ((sel == 1) ? C1v : C2v);
    const int ncol0 = bnG - sel * 768;

    const int tid  = threadIdx.x;
    const int lane = tid & 63;
    const int wave = tid >> 6;
    const int wm = wave >> 1, wn = wave & 1;

    f32x4 acc[4][4];
    #pragma unroll
    for (int i = 0; i < 4; i++)
        #pragma unroll
        for (int j = 0; j < 4; j++)
            acc[i][j] = (f32x4){0.f, 0.f, 0.f, 0.f};

    const int sr = tid >> 2;
    const int sk = (tid & 3) * 8;
    const ushort* Ap = A  + (size_t)(bm  + sr) * 768 + sk;
    const ushort* Bp = BT + (size_t)(bnG + sr) * 768 + sk;
    char* AsDst = (char*)As + tid * 16;
    char* BsDst = (char*)Bs + tid * 16;

    for (int k0 = 0; k0 < 768; k0 += 32) {
        __syncthreads();
        __builtin_amdgcn_global_load_lds(
            (const __attribute__((address_space(1))) void*)(Ap + k0),
            (__attribute__((address_space(3))) void*)AsDst, 16, 0, 0);
        __builtin_amdgcn_global_load_lds(
            (const __attribute__((address_space(1))) void*)(Ap + (size_t)64 * 768 + k0),
            (__attribute__((address_space(3))) void*)(AsDst + 4096), 16, 0, 0);
        __builtin_amdgcn_global_load_lds(
            (const __attribute__((address_space(1))) void*)(Bp + k0),
            (__attribute__((address_space(3))) void*)BsDst, 16, 0, 0);
        __builtin_amdgcn_global_load_lds(
            (const __attribute__((address_space(1))) void*)(Bp + (size_t)64 * 768 + k0),
            (__attribute__((address_space(3))) void*)(BsDst + 4096), 16, 0, 0);
        __syncthreads();

        short8v a[4], b[4];
        #pragma unroll
        for (int i = 0; i < 4; i++)
            a[i] = *(const short8v*)((const char*)As +
                     (wm * 64 + i * 16 + (lane & 15)) * 64 + (lane >> 4) * 16);
        #pragma unroll
        for (int j = 0; j < 4; j++)
            b[j] = *(const short8v*)((const char*)Bs +
                     (wn * 64 + j * 16 + (lane & 15)) * 64 + (lane >> 4) * 16);
        #pragma unroll
        for (int i = 0; i < 4; i++)
            #pragma unroll
            for (int j = 0; j < 4; j++)
                acc[i][j] = __builtin_amdgcn_mfma_f32_16x16x32_bf16(a[i], b[j], acc[i][j], 0, 0, 0);
    }

    const int cc = lane & 15, cr = lane >> 4;
    if (BF16OUT && VT != nullptr && sel == 2) {
        #pragma unroll
        for (int j = 0; j < 4; j++) {
            const int hcol = ncol0 + wn * 64 + j * 16 + cc;
            const int h2 = hcol >> 6, dd = hcol & 63;
            #pragma unroll
            for (int i = 0; i < 4; i++) {
                const int row0 = bm + wm * 64 + i * 16 + cr * 4;
                const int bb = row0 >> 10, jj = row0 & 1023;
                ushort4 o;
                o.x = f2bf(acc[i][j][0]); o.y = f2bf(acc[i][j][1]);
                o.z = f2bf(acc[i][j][2]); o.w = f2bf(acc[i][j][3]);
                *(ushort4*)(VT + (((size_t)bb * NHEAD + h2) * HDIM + dd) * SEQ + jj) = o;
            }
        }
        return;
    }
    #pragma unroll
    for (int j = 0; j < 4; j++) {
        const int col = ncol0 + wn * 64 + j * 16 + cc;
        const float badd = bias ? bias[col] : 0.f;
        #pragma unroll
        for (int i = 0; i < 4; i++) {
            #pragma unroll
            for (int r = 0; r < 4; r++) {
                const int row = bm + wm * 64 + i * 16 + cr * 4 + r;
                if (BF16OUT)
                    ((ushort*)Cv)[(size_t)row * 768 + col] = f2bf(acc[i][j][r] + badd);
                else
                    ((float*)Cv)[(size_t)row * 768 + col] = acc[i][j][r] + badd;
            }
        }
    }
}

// ---------------------------------------------------------------------------
// Talking-heads attention v5 — per-ELEMENT head-mix (12x less LDS traffic).
// 1024 threads = 16 waves. Waves 0-11: QK^T + PV (one head each).
// ALL 16 waves: mix — wave w owns row i=w, lane owns col j.
// S layout [i][j][13] (+row pad): each element's 12 head-values contiguous,
// read ONCE per mix; 144-FMA pre-mix and post-mix fully in-register
// (weights broadcast from padded [12][16] LDS rows as float4).
// Phase B writes only final bf16 P[g][i][j] for the PV A-frags.
// ---------------------------------------------------------------------------
__global__ __launch_bounds__(1024, 1) void attn_mfma_kernel(
    const ushort* __restrict__ qb, const ushort* __restrict__ kb,
    const ushort* __restrict__ vt, const float* __restrict__ pre_attn,
    const float* __restrict__ post_attn, ushort* __restrict__ avb)
{
    __shared__ __align__(16) float S0[QBLK * SPITCH];     // 53.4 KB
    __shared__ __align__(16) float S1[QBLK * SPITCH];     // 53.4 KB
    __shared__ __align__(16) ushort P[NHEAD][QBLK][72];   // 27.6 KB (144B rows, 16B-aligned)
    __shared__ __align__(16) float prew[NHEAD][16];
    __shared__ __align__(16) float postw[NHEAD][16];
    __shared__ float l_lds[NHEAD][QBLK];

    const int i0  = blockIdx.x * QBLK;
    const int b   = blockIdx.y;
    const int tid = threadIdx.x;
    const int lane = tid & 63;
    const int w    = tid >> 6;          // wave: head (w<12) and mix-row i=w

    // fold 1/sqrt(64) and log2(e) into pre so exp(mix) == exp2(mix')
    if (tid < 144) prew[tid / 12][tid % 12] = pre_attn[tid] * (0.125f * 1.44269504f);
    else if (tid < 288) { int t2 = tid - 144; postw[t2 / 12][t2 % 12] = post_attn[t2]; }

    const int lr = lane & 15, lc = lane >> 4;

    short8v a_q0 = {0,0,0,0,0,0,0,0}, a_q1 = {0,0,0,0,0,0,0,0};
    const ushort* kbase  = kb;
    const ushort* vtbase = vt;
    if (w < NHEAD) {
        const ushort* qbase = qb + ((size_t)b * SEQ + i0 + lr) * D_MODEL + w * HDIM + lc * 8;
        a_q0 = *(const short8v*)(qbase);
        a_q1 = *(const short8v*)(qbase + 32);
        kbase  = kb + ((size_t)b * SEQ + lr) * D_MODEL + w * HDIM + lc * 8;
        vtbase = vt + (((size_t)b * NHEAD + w) * HDIM + lr) * SEQ + lc * 8;
    }
    __syncthreads();   // prew/postw visible

    // ======================= Phase A: row sums =======================
    float el[NHEAD];
    #pragma unroll
    for (int g = 0; g < NHEAD; g++) el[g] = 0.f;

    for (int t = 0; t < NT; t++) {
        float* S = (t & 1) ? S1 : S0;
        if (w < NHEAD) {
            const int j0 = t * KVBLK;
            #pragma unroll
            for (int cf = 0; cf < 4; cf++) {
                const ushort* kp = kbase + (size_t)(j0 + cf * 16) * D_MODEL;
                short8v bk0 = *(const short8v*)(kp);
                short8v bk1 = *(const short8v*)(kp + 32);
                f32x4 a = (f32x4){0.f, 0.f, 0.f, 0.f};
                a = __builtin_amdgcn_mfma_f32_16x16x32_bf16(a_q0, bk0, a, 0, 0, 0);
                a = __builtin_amdgcn_mfma_f32_16x16x32_bf16(a_q1, bk1, a, 0, 0, 0);
                #pragma unroll
                for (int rr = 0; rr < 4; rr++)
                    S[(lc * 4 + rr) * SPITCH + (cf * 16 + lr) * 13 + w] = a[rr];
            }
        }
        __syncthreads();

        const float* sp = S + w * SPITCH + lane * 13;
        float mv[NHEAD];
        #pragma unroll
        for (int g = 0; g < NHEAD; g++) mv[g] = 0.f;
        #pragma unroll
        for (int hh = 0; hh < NHEAD; hh++) {
            const float s = sp[hh];
            const float4 w0 = *(const float4*)&prew[hh][0];
            const float4 w1 = *(const float4*)&prew[hh][4];
            const float4 w2 = *(const float4*)&prew[hh][8];
            mv[0] = fmaf(s, w0.x, mv[0]); mv[1]  = fmaf(s, w0.y, mv[1]);
            mv[2] = fmaf(s, w0.z, mv[2]); mv[3]  = fmaf(s, w0.w, mv[3]);
            mv[4] = fmaf(s, w1.x, mv[4]); mv[5]  = fmaf(s, w1.y, mv[5]);
            mv[6] = fmaf(s, w1.z, mv[6]); mv[7]  = fmaf(s, w1.w, mv[7]);
            mv[8] = fmaf(s, w2.x, mv[8]); mv[9]  = fmaf(s, w2.y, mv[9]);
            mv[10] = fmaf(s, w2.z, mv[10]); mv[11] = fmaf(s, w2.w, mv[11]);
        }
        #pragma unroll
        for (int g = 0; g < NHEAD; g++) el[g] += exp2f(mv[g]);
    }

    #pragma unroll
    for (int g = 0; g < NHEAD; g++) {
        float v = el[g];
        v += __shfl_xor(v, 1);  v += __shfl_xor(v, 2);  v += __shfl_xor(v, 4);
        v += __shfl_xor(v, 8);  v += __shfl_xor(v, 16); v += __shfl_xor(v, 32);
        if (lane == 0) l_lds[g][w] = v;
    }
    __syncthreads();

    float il[NHEAD];
    #pragma unroll
    for (int g = 0; g < NHEAD; g++) il[g] = 1.f / l_lds[g][w];

    // ======================= Phase B: P + PV =======================
    f32x4 o_acc[4];
    #pragma unroll
    for (int d = 0; d < 4; d++) o_acc[d] = (f32x4){0.f, 0.f, 0.f, 0.f};

    for (int t = 0; t < NT; t++) {
        const int j0 = t * KVBLK;
        if (w < NHEAD) {
            #pragma unroll
            for (int cf = 0; cf < 4; cf++) {
                const ushort* kp = kbase + (size_t)(j0 + cf * 16) * D_MODEL;
                short8v bk0 = *(const short8v*)(kp);
                short8v bk1 = *(const short8v*)(kp + 32);
                f32x4 a = (f32x4){0.f, 0.f, 0.f, 0.f};
                a = __builtin_amdgcn_mfma_f32_16x16x32_bf16(a_q0, bk0, a, 0, 0, 0);
                a = __builtin_amdgcn_mfma_f32_16x16x32_bf16(a_q1, bk1, a, 0, 0, 0);
                #pragma unroll
                for (int rr = 0; rr < 4; rr++)
                    S0[(lc * 4 + rr) * SPITCH + (cf * 16 + lr) * 13 + w] = a[rr];
            }
        }
        __syncthreads();                       // bar1: S ready (and prior PV done)

        const float* sp = S0 + w * SPITCH + lane * 13;
        float mv[NHEAD];
        #pragma unroll
        for (int g = 0; g < NHEAD; g++) mv[g] = 0.f;
        #pragma unroll
        for (int hh = 0; hh < NHEAD; hh++) {
            const float s = sp[hh];
            const float4 w0 = *(const float4*)&prew[hh][0];
            const float4 w1 = *(const float4*)&prew[hh][4];
            const float4 w2 = *(const float4*)&prew[hh][8];
            mv[0] = fmaf(s, w0.x, mv[0]); mv[1]  = fmaf(s, w0.y, mv[1]);
            mv[2] = fmaf(s, w0.z, mv[2]); mv[3]  = fmaf(s, w0.w, mv[3]);
            mv[4] = fmaf(s, w1.x, mv[4]); mv[5]  = fmaf(s, w1.y, mv[5]);
            mv[6] = fmaf(s, w1.z, mv[6]); mv[7]  = fmaf(s, w1.w, mv[7]);
            mv[8] = fmaf(s, w2.x, mv[8]); mv[9]  = fmaf(s, w2.y, mv[9]);
            mv[10] = fmaf(s, w2.z, mv[10]); mv[11] = fmaf(s, w2.w, mv[11]);
        }
        // exp (identical op order to phase A) then fold 1/l per source head
        #pragma unroll
        for (int g = 0; g < NHEAD; g++) mv[g] = exp2f(mv[g]) * il[g];

        float pm[NHEAD];
        #pragma unroll
        for (int g = 0; g < NHEAD; g++) pm[g] = 0.f;
        #pragma unroll
        for (int hh = 0; hh < NHEAD; hh++) {
            const float s = mv[hh];
            const float4 w0 = *(const float4*)&postw[hh][0];
            const float4 w1 = *(const float4*)&postw[hh][4];
            const float4 w2 = *(const float4*)&postw[hh][8];
            pm[0] = fmaf(s, w0.x, pm[0]); pm[1]  = fmaf(s, w0.y, pm[1]);
            pm[2] = fmaf(s, w0.z, pm[2]); pm[3]  = fmaf(s, w0.w, pm[3]);
            pm[4] = fmaf(s, w1.x, pm[4]); pm[5]  = fmaf(s, w1.y, pm[5]);
            pm[6] = fmaf(s, w1.z, pm[6]); pm[7]  = fmaf(s, w1.w, pm[7]);
            pm[8] = fmaf(s, w2.x, pm[8]); pm[9]  = fmaf(s, w2.y, pm[9]);
            pm[10] = fmaf(s, w2.z, pm[10]); pm[11] = fmaf(s, w2.w, pm[11]);
        }
        #pragma unroll
        for (int g = 0; g < NHEAD; g++)
            P[g][w][lane] = f2bf(pm[g]);
        __syncthreads();                       // bar2: P ready

        if (w < NHEAD) {
            short8v pa0 = *(const short8v*)&P[w][lr][lc * 8];
            short8v pa1 = *(const short8v*)&P[w][lr][lc * 8 + 32];
            #pragma unroll
            for (int d = 0; d < 4; d++) {
                short8v bv0 = *(const short8v*)(vtbase + (size_t)(d * 16) * SEQ + j0);
                short8v bv1 = *(const short8v*)(vtbase + (size_t)(d * 16) * SEQ + j0 + 32);
                o_acc[d] = __builtin_amdgcn_mfma_f32_16x16x32_bf16(pa0, bv0, o_acc[d], 0, 0, 0);
                o_acc[d] = __builtin_amdgcn_mfma_f32_16x16x32_bf16(pa1, bv1, o_acc[d], 0, 0, 0);
            }
        }
    }

    if (w < NHEAD) {
        #pragma unroll
        for (int d = 0; d < 4; d++)
            #pragma unroll
            for (int rr = 0; rr < 4; rr++)
                avb[(((size_t)b * NHEAD + w) * SEQ + i0 + lc * 4 + rr) * HDIM + d * 16 + lr]
                    = f2bf(o_acc[d][rr]);
    }
}

// ---------------------------------------------------------------------------
extern "C" void kernel_launch(void* const* d_in, const int* in_sizes, int n_in,
                              void* d_out, int out_size, void* d_ws, size_t ws_size,
                              hipStream_t stream)
{
    const float* x    = (const float*)d_in[0];
    const float* Wq   = (const float*)d_in[1];
    const float* Wk   = (const float*)d_in[2];
    const float* Wv   = (const float*)d_in[3];
    const float* pre  = (const float*)d_in[4];
    const float* post = (const float*)d_in[5];
    const float* Wo   = (const float*)d_in[6];
    const float* bo   = (const float*)d_in[7];
    float* out = (float*)d_out;

    const size_t SZ = (size_t)BATCH * SEQ * D_MODEL;   // 3,145,728
    ushort* qbf    = (ushort*)d_ws;
    ushort* kbf    = qbf + SZ;
    ushort* vt     = kbf + SZ;              // [b][h][d][j] written by GEMM epilogue
    ushort* xb_avb = vt  + SZ;              // x_bf16 for QKV GEMM, av_bf16 after
    ushort* qkvT   = xb_avb + SZ;           // [2304][768]: WqT|WkT|WvT
    ushort* WoT    = qkvT + (size_t)2304 * 768;
    // total 29.9 MB

    cast_bf16_kernel<<<(int)(SZ / 4 + 255) / 256, 256, 0, stream>>>(x, xb_avb, (int)(SZ / 4));
    castT4_kernel<<<dim3(24, 24, 4), 256, 0, stream>>>(
        Wq, Wk, Wv, Wo,
        qkvT, qkvT + (size_t)768 * 768, qkvT + (size_t)2 * 768 * 768, WoT);

    // fused QKV projection; V slice written transposed into vt
    gemm_bf16_kernel<1><<<dim3(32, 18), 256, 0, stream>>>(
        xb_avb, qkvT, qbf, kbf, nullptr, nullptr, vt);

    attn_mfma_kernel<<<dim3(SEQ / QBLK, BATCH), 1024, 0, stream>>>(
        qbf, kbf, vt, pre, post, xb_avb);

    gemm_bf16_kernel<0><<<dim3(32, 6), 256, 0, stream>>>(
        xb_avb, WoT, out, out, out, bo, nullptr);
}